// Round 1
// 1012.625 us; speedup vs baseline: 1.0792x; 1.0792x over previous
//
#include <hip/hip_runtime.h>
#include <cmath>

#define B_ 4
#define T_ 4096
#define D_ 1024

typedef __attribute__((ext_vector_type(4))) float f32x4;
typedef __attribute__((ext_vector_type(2))) float f32x2;
typedef __attribute__((ext_vector_type(8))) short s16x8;

__device__ __forceinline__ f32x4 mfma_bf16(s16x8 a, s16x8 b, f32x4 c) {
    return __builtin_amdgcn_mfma_f32_16x16x32_bf16(a, b, c, 0, 0, 0);
}
__device__ __forceinline__ unsigned short f2bf(float f) {
    union { float f; unsigned int u; } v; v.f = f;
    unsigned int r = v.u + 0x7FFFu + ((v.u >> 16) & 1u);
    return (unsigned short)(r >> 16);
}

// ---------------- kernel 1: repack fp32 weights to bf16 w_t[p][h][d][i] ----
__global__ __launch_bounds__(256) void k_wtrans(const float* __restrict__ wq,
                                                const float* __restrict__ wk,
                                                const float* __restrict__ wv,
                                                unsigned short* __restrict__ wt) {
    int p = blockIdx.x >> 4;   // 0..2
    int h = blockIdx.x & 15;
    const float* src = (p == 0) ? wq : (p == 1) ? wk : wv;
    unsigned short* dst = wt + (size_t)((p * 16 + h) * 64) * 64;
    for (int idx = threadIdx.x; idx < 64 * 64; idx += 256) {
        int d = idx >> 6, i = idx & 63;
        dst[d * 64 + i] = f2bf(src[i * 1024 + d * 16 + h]);   // w[i][d][h]
    }
}

// ---------------- kernel 2: QKV projection + fused RoPE ---------------------
// block: 256 thr (4 waves), handles (b, head-pair hp, 64 tokens).
// Q_t,K_t: [b][h][t][d] (d-contig).  V_t: [b][h][d][t] (t-contig).  All bf16.
// bid map: hp in HIGH bits so the 8 hp-blocks sharing an x-tile land on the
// SAME XCD (bid%8 == (b*64+tc)%8 independent of hp) -> x cachelines (which
// interleave all 16 heads) are L2-reused 8x instead of re-fetched per XCD.
__global__ __launch_bounds__(256) void k_qkv(const float* __restrict__ x,
                                             const unsigned short* __restrict__ wt,
                                             unsigned short* __restrict__ Qt,
                                             unsigned short* __restrict__ Kt,
                                             unsigned short* __restrict__ Vt) {
    int bid = blockIdx.x;
    int hp  = bid >> 8;          // head pair 0..7
    int b   = (bid >> 6) & 3;
    int tc  = bid & 63;          // token chunk
    int t0  = tc * 64;
    int tid = threadIdx.x, w = tid >> 6, lane = tid & 63;
    int quad = lane >> 4, l16 = lane & 15;

    __shared__ alignas(16) unsigned short xh[2 * 64 * 72];   // [hh][t][i], pad 72
    __shared__ alignas(16) unsigned short outl[64 * 68];     // staging tile, pad 68

    // the two hh values are adjacent in x (e = i*16 + 2hp + hh) -> f32x2 load
    for (int n = tid; n < 4096; n += 256) {
        int t = n >> 6, i = n & 63;
        f32x2 v = *(const f32x2*)&x[(size_t)(b * T_ + t0 + t) * D_ + i * 16 + 2 * hp];
        xh[t * 72 + i]        = f2bf(v.x);
        xh[4608 + t * 72 + i] = f2bf(v.y);
    }
    __syncthreads();

    s16x8 xf[2][2];
    #pragma unroll
    for (int hh = 0; hh < 2; ++hh)
        #pragma unroll
        for (int kc = 0; kc < 2; ++kc)
            xf[hh][kc] = *(const s16x8*)&xh[hh * 4608 + (16 * w + l16) * 72 + kc * 32 + quad * 8];

    f32x4 acc[3][2][4];
    #pragma unroll
    for (int p = 0; p < 3; ++p)
        #pragma unroll
        for (int hh = 0; hh < 2; ++hh)
            #pragma unroll
            for (int nt = 0; nt < 4; ++nt)
                acc[p][hh][nt] = (f32x4){0.f, 0.f, 0.f, 0.f};

    #pragma unroll
    for (int p = 0; p < 3; ++p)
        #pragma unroll
        for (int hh = 0; hh < 2; ++hh)
            #pragma unroll
            for (int nt = 0; nt < 4; ++nt)
                #pragma unroll
                for (int kc = 0; kc < 2; ++kc) {
                    const s16x8 wf = *(const s16x8*)&wt[
                        (size_t)((p * 16 + 2 * hp + hh) * 64 + nt * 16 + l16) * 64 + kc * 32 + quad * 8];
                    if (p < 2)  // Q,K: C[t][d] = X[t][i] * W[i][d]
                        acc[p][hh][nt] = mfma_bf16(xf[hh][kc], wf, acc[p][hh][nt]);
                    else        // V: C[d][t] = W^T[d][i] * X^T[i][t]
                        acc[p][hh][nt] = mfma_bf16(wf, xf[hh][kc], acc[p][hh][nt]);
                }

    // fused RoPE on Q,K: pairs (d, h0)<->(d, h0+1), j = d*8 + hp
    #pragma unroll
    for (int nt = 0; nt < 4; ++nt) {
        int d = nt * 16 + l16;
        float f = exp2f((float)(d * 8 + hp) * -0.02595256324130751f); // -log2(1e4)/512
        #pragma unroll
        for (int r = 0; r < 4; ++r) {
            float ang = (float)(t0 + 16 * w + quad * 4 + r) * f;
            float s, c;
            sincosf(ang, &s, &c);
            float a0 = acc[0][0][nt][r], a1 = acc[0][1][nt][r];
            acc[0][0][nt][r] = a0 * c - a1 * s;
            acc[0][1][nt][r] = a0 * s + a1 * c;
            float k0 = acc[1][0][nt][r], k1 = acc[1][1][nt][r];
            acc[1][0][nt][r] = k0 * c - k1 * s;
            acc[1][1][nt][r] = k0 * s + k1 * c;
        }
    }

    // store 6 tiles (Q,K as [t][d]; V as [d][t]) via LDS for coalescing
    #pragma unroll
    for (int p = 0; p < 3; ++p)
        #pragma unroll
        for (int hh = 0; hh < 2; ++hh) {
            __syncthreads();
            if (p < 2) {
                #pragma unroll
                for (int nt = 0; nt < 4; ++nt)
                    #pragma unroll
                    for (int r = 0; r < 4; ++r)
                        outl[(16 * w + quad * 4 + r) * 68 + nt * 16 + l16] = f2bf(acc[p][hh][nt][r]);
            } else {
                #pragma unroll
                for (int mt = 0; mt < 4; ++mt)
                    #pragma unroll
                    for (int r = 0; r < 4; ++r)
                        outl[(mt * 16 + quad * 4 + r) * 68 + 16 * w + l16] = f2bf(acc[p][hh][mt][r]);
            }
            __syncthreads();
            int h = 2 * hp + hh;
            if (p < 2) {
                unsigned short* g = (p == 0 ? Qt : Kt) + ((size_t)(b * 16 + h) * T_ + t0) * 64;
                for (int n = 2 * tid; n < 4096; n += 512) {
                    int t = n >> 6, dd = n & 63;
                    *(unsigned int*)(g + n) = *(const unsigned int*)&outl[t * 68 + dd];
                }
            } else {
                unsigned short* g = Vt + (size_t)(b * 16 + h) * 64 * T_;
                for (int n = 2 * tid; n < 4096; n += 512) {
                    int d = n >> 6, tt = n & 63;
                    *(unsigned int*)(g + d * T_ + t0 + tt) = *(const unsigned int*)&outl[d * 68 + tt];
                }
            }
        }
}

// ---------------- kernel 3: flash attention (software-pipelined) -----------
// block: 512 thr (8 waves), 32 q-rows. Wave w owns d-slice [128w,128w+128).
// Pipeline per k-tile:
//   phase A: issue V(kt) + K(kt+1) global loads, then softmax(kt)  (loads
//            drain under ~500cy of reduce/shfl/exp work at the A barrier)
//   phase B: PV(kt) MFMA with vf regs + S(kt+1) MFMA with kn regs
// so no phase starts with an exposed global-latency stall.
__global__ __launch_bounds__(512) void k_attn(const unsigned short* __restrict__ Qt,
                                              const unsigned short* __restrict__ Kt,
                                              const unsigned short* __restrict__ Vt,
                                              float* __restrict__ out) {
    int bid = blockIdx.x;
    int j = bid >> 2, b = bid & 3;
    int qt = (bid < 256) ? (127 - j) : (j - 64);   // heavy blocks first (causal balance)
    int q0 = qt * 32;
    int tid = threadIdx.x, w = tid >> 6, lane = tid & 63;
    int quad = lane >> 4, l16 = lane & 15;

    __shared__ alignas(16) float S_red[8][32][36];          // partial S^T per wave, padded
    __shared__ alignas(16) unsigned short P_lds[32][40];    // P[q][kpos] bf16, padded
    __shared__ float m_st[32], l_st[32], alpha_s[32];

    if (tid < 32) { m_st[tid] = -INFINITY; l_st[tid] = 0.f; }

    // Q fragments (loop-invariant): B-operand, [q][d] d-contig
    s16x8 qf[2][4];
    #pragma unroll
    for (int qs = 0; qs < 2; ++qs)
        #pragma unroll
        for (int c = 0; c < 4; ++c) {
            int dg = w * 128 + c * 32 + quad * 8;
            int head = dg >> 6, d64 = dg & 63;
            qf[qs][c] = *(const s16x8*)&Qt[((size_t)(b * 16 + head) * T_ + q0 + qs * 16 + l16) * 64 + d64];
        }

    f32x4 Y[8][2];
    #pragma unroll
    for (int mt = 0; mt < 8; ++mt) { Y[mt][0] = (f32x4){0,0,0,0}; Y[mt][1] = (f32x4){0,0,0,0}; }

    const float gamma = 0.03125f;   // 1/sqrt(1024)
    int rq = tid >> 4;              // reduction-phase row 0..31 (16 lanes per row)
    int kk = (tid & 15) * 2;
    int nkt = qt + 1;

    // ---- prologue: S(0) into S_red ----
    {
        f32x4 S[2][2];
        S[0][0] = (f32x4){0,0,0,0}; S[0][1] = (f32x4){0,0,0,0};
        S[1][0] = (f32x4){0,0,0,0}; S[1][1] = (f32x4){0,0,0,0};
        #pragma unroll
        for (int kps = 0; kps < 2; ++kps)
            #pragma unroll
            for (int c = 0; c < 4; ++c) {
                int dg = w * 128 + c * 32 + quad * 8;
                int head = dg >> 6, d64 = dg & 63;
                s16x8 kf = *(const s16x8*)&Kt[((size_t)(b * 16 + head) * T_ + kps * 16 + l16) * 64 + d64];
                S[kps][0] = mfma_bf16(kf, qf[0][c], S[kps][0]);
                S[kps][1] = mfma_bf16(kf, qf[1][c], S[kps][1]);
            }
        #pragma unroll
        for (int kps = 0; kps < 2; ++kps)
            #pragma unroll
            for (int qs = 0; qs < 2; ++qs)
                *(f32x4*)&S_red[w][qs * 16 + l16][kps * 16 + quad * 4] = S[kps][qs];
    }
    __syncthreads();

    s16x8 vf[8];        // V(kt) fragments, loaded in phase A(kt)
    s16x8 kn[2][4];     // K(kt+1) fragments, loaded in phase A(kt)

    for (int kt = 0; kt < nkt; ++kt) {
        int kbase = kt * 32;
        bool more = (kt + 1 < nkt);

        // ---- phase A: prefetch V(kt) + K(kt+1), then softmax(kt) ----
        #pragma unroll
        for (int mt = 0; mt < 8; ++mt) {
            int dg = w * 128 + mt * 16 + l16;
            int head = dg >> 6, d64 = dg & 63;
            vf[mt] = *(const s16x8*)&Vt[((size_t)(b * 16 + head) * 64 + d64) * T_ + kbase + quad * 8];
        }
        if (more) {
            #pragma unroll
            for (int kps = 0; kps < 2; ++kps)
                #pragma unroll
                for (int c = 0; c < 4; ++c) {
                    int dg = w * 128 + c * 32 + quad * 8;
                    int head = dg >> 6, d64 = dg & 63;
                    kn[kps][c] = *(const s16x8*)&Kt[
                        ((size_t)(b * 16 + head) * T_ + kbase + 32 + kps * 16 + l16) * 64 + d64];
                }
        }

        float s0 = 0.f, s1 = 0.f;
        #pragma unroll
        for (int sl = 0; sl < 8; ++sl) {
            f32x2 v = *(const f32x2*)&S_red[sl][rq][kk];
            s0 += v.x; s1 += v.y;
        }
        s0 *= gamma; s1 *= gamma;
        int qg = q0 + rq;
        if (kbase + kk > qg)     s0 = -INFINITY;
        if (kbase + kk + 1 > qg) s1 = -INFINITY;
        float mx = fmaxf(s0, s1);
        mx = fmaxf(mx, __shfl_xor(mx, 1));
        mx = fmaxf(mx, __shfl_xor(mx, 2));
        mx = fmaxf(mx, __shfl_xor(mx, 4));
        mx = fmaxf(mx, __shfl_xor(mx, 8));
        float m_old = m_st[rq];
        float m_new = fmaxf(m_old, mx);
        float alpha = __expf(m_old - m_new);
        float p0 = __expf(s0 - m_new), p1 = __expf(s1 - m_new);
        float ps = p0 + p1;
        ps += __shfl_xor(ps, 1); ps += __shfl_xor(ps, 2);
        ps += __shfl_xor(ps, 4); ps += __shfl_xor(ps, 8);
        if ((tid & 15) == 0) {
            l_st[rq] = alpha * l_st[rq] + ps;
            m_st[rq] = m_new;
            alpha_s[rq] = alpha;
        }
        unsigned int pp = (unsigned int)f2bf(p0) | ((unsigned int)f2bf(p1) << 16);
        *(unsigned int*)&P_lds[rq][kk] = pp;
        __syncthreads();

        // ---- phase B: PV(kt) with vf regs + S(kt+1) with kn regs ----
        float a0 = alpha_s[l16], a1 = alpha_s[16 + l16];
        s16x8 pf0 = *(const s16x8*)&P_lds[l16][quad * 8];
        s16x8 pf1 = *(const s16x8*)&P_lds[16 + l16][quad * 8];
        // skip the Y-rescale (128 AGPR-touching VALU ops) when no row's max
        // grew this tile (alpha==1 exactly) — exact, wave-uniform branch.
        int scale = __any((a0 < 1.f) || (a1 < 1.f));
        __builtin_amdgcn_s_setprio(1);
        if (scale) {
            #pragma unroll
            for (int mt = 0; mt < 8; ++mt) {
                Y[mt][0] *= a0;
                Y[mt][1] *= a1;
                Y[mt][0] = mfma_bf16(vf[mt], pf0, Y[mt][0]);
                Y[mt][1] = mfma_bf16(vf[mt], pf1, Y[mt][1]);
            }
        } else {
            #pragma unroll
            for (int mt = 0; mt < 8; ++mt) {
                Y[mt][0] = mfma_bf16(vf[mt], pf0, Y[mt][0]);
                Y[mt][1] = mfma_bf16(vf[mt], pf1, Y[mt][1]);
            }
        }
        if (more) {
            f32x4 S[2][2];
            S[0][0] = (f32x4){0,0,0,0}; S[0][1] = (f32x4){0,0,0,0};
            S[1][0] = (f32x4){0,0,0,0}; S[1][1] = (f32x4){0,0,0,0};
            #pragma unroll
            for (int kps = 0; kps < 2; ++kps)
                #pragma unroll
                for (int c = 0; c < 4; ++c) {
                    S[kps][0] = mfma_bf16(kn[kps][c], qf[0][c], S[kps][0]);
                    S[kps][1] = mfma_bf16(kn[kps][c], qf[1][c], S[kps][1]);
                }
            #pragma unroll
            for (int kps = 0; kps < 2; ++kps)
                #pragma unroll
                for (int qs = 0; qs < 2; ++qs)
                    *(f32x4*)&S_red[w][qs * 16 + l16][kps * 16 + quad * 4] = S[kps][qs];
        }
        __builtin_amdgcn_s_setprio(0);
        __syncthreads();
    }

    // ---- epilogue: normalize, map d->(h,d64)->e, store fp32 ----
    float inv0 = 1.f / l_st[l16], inv1 = 1.f / l_st[16 + l16];
    #pragma unroll
    for (int mt = 0; mt < 8; ++mt)
        #pragma unroll
        for (int r = 0; r < 4; ++r) {
            int dg = w * 128 + mt * 16 + quad * 4 + r;
            int head = dg >> 6, d64 = dg & 63;
            int e = d64 * 16 + head;
            out[(size_t)(b * T_ + q0 + l16) * D_ + e]      = Y[mt][0][r] * inv0;
            out[(size_t)(b * T_ + q0 + 16 + l16) * D_ + e] = Y[mt][1][r] * inv1;
        }
}

extern "C" void kernel_launch(void* const* d_in, const int* in_sizes, int n_in,
                              void* d_out, int out_size, void* d_ws, size_t ws_size,
                              hipStream_t stream) {
    const float* x  = (const float*)d_in[0];
    const float* wq = (const float*)d_in[1];
    const float* wk = (const float*)d_in[2];
    const float* wv = (const float*)d_in[3];
    unsigned short* ws = (unsigned short*)d_ws;

    // workspace layout (bf16 elements)
    const size_t WT_ELEMS  = 3 * 16 * 64 * 64;          // 196608
    const size_t QKV_ELEMS = (size_t)B_ * 16 * T_ * 64; // 16777216 each
    const size_t NEED_BYTES = (WT_ELEMS + 3 * QKV_ELEMS) * sizeof(unsigned short);
    if (ws_size < NEED_BYTES) return;

    unsigned short* wt = ws;
    unsigned short* Qt = ws + WT_ELEMS;
    unsigned short* Kt = Qt + QKV_ELEMS;
    unsigned short* Vt = Kt + QKV_ELEMS;
    float* outp = (float*)d_out;

    k_wtrans<<<48, 256, 0, stream>>>(wq, wk, wv, wt);
    k_qkv<<<2048, 256, 0, stream>>>(x, wt, Qt, Kt, Vt);
    k_attn<<<512, 512, 0, stream>>>(Qt, Kt, Vt, outp);
}

// Round 2
// 1005.727 us; speedup vs baseline: 1.0866x; 1.0069x over previous
//
#include <hip/hip_runtime.h>
#include <cmath>

#define B_ 4
#define T_ 4096
#define D_ 1024

typedef __attribute__((ext_vector_type(4))) float f32x4;
typedef __attribute__((ext_vector_type(2))) float f32x2;
typedef __attribute__((ext_vector_type(8))) short s16x8;

__device__ __forceinline__ f32x4 mfma_bf16(s16x8 a, s16x8 b, f32x4 c) {
    return __builtin_amdgcn_mfma_f32_16x16x32_bf16(a, b, c, 0, 0, 0);
}
__device__ __forceinline__ unsigned short f2bf(float f) {
    union { float f; unsigned int u; } v; v.f = f;
    unsigned int r = v.u + 0x7FFFu + ((v.u >> 16) & 1u);
    return (unsigned short)(r >> 16);
}

// ---------------- kernel 1: repack fp32 weights to bf16 w_t[p][h][d][i] ----
__global__ __launch_bounds__(256) void k_wtrans(const float* __restrict__ wq,
                                                const float* __restrict__ wk,
                                                const float* __restrict__ wv,
                                                unsigned short* __restrict__ wt) {
    int p = blockIdx.x >> 4;   // 0..2
    int h = blockIdx.x & 15;
    const float* src = (p == 0) ? wq : (p == 1) ? wk : wv;
    unsigned short* dst = wt + (size_t)((p * 16 + h) * 64) * 64;
    for (int idx = threadIdx.x; idx < 64 * 64; idx += 256) {
        int d = idx >> 6, i = idx & 63;
        dst[d * 64 + i] = f2bf(src[i * 1024 + d * 16 + h]);   // w[i][d][h]
    }
}

// ---------------- kernel 2: QKV projection + fused RoPE ---------------------
// block: 256 thr (4 waves), handles (b, head-pair hp, 64 tokens).
// Q_t,K_t: [b][h][t][d] (d-contig).  V_t: [b][h][d][t] (t-contig).  All bf16.
// launch_bounds (256,3): acc[3][2][4] f32x4 alone is 96 VGPRs; the default
// 128-reg budget spills. 512/3 ~= 170 regs fits demand, keeps 3 blocks/CU.
__global__ __launch_bounds__(256, 3) void k_qkv(const float* __restrict__ x,
                                             const unsigned short* __restrict__ wt,
                                             unsigned short* __restrict__ Qt,
                                             unsigned short* __restrict__ Kt,
                                             unsigned short* __restrict__ Vt) {
    int bid = blockIdx.x;
    int hp  = bid >> 8;          // head pair 0..7
    int b   = (bid >> 6) & 3;
    int tc  = bid & 63;          // token chunk
    int t0  = tc * 64;
    int tid = threadIdx.x, w = tid >> 6, lane = tid & 63;
    int quad = lane >> 4, l16 = lane & 15;

    __shared__ alignas(16) unsigned short xh[2 * 64 * 72];   // [hh][t][i], pad 72
    __shared__ alignas(16) unsigned short outl[64 * 68];     // staging tile, pad 68

    // the two hh values are adjacent in x (e = i*16 + 2hp + hh) -> f32x2 load
    for (int n = tid; n < 4096; n += 256) {
        int t = n >> 6, i = n & 63;
        f32x2 v = *(const f32x2*)&x[(size_t)(b * T_ + t0 + t) * D_ + i * 16 + 2 * hp];
        xh[t * 72 + i]        = f2bf(v.x);
        xh[4608 + t * 72 + i] = f2bf(v.y);
    }
    __syncthreads();

    s16x8 xf[2][2];
    #pragma unroll
    for (int hh = 0; hh < 2; ++hh)
        #pragma unroll
        for (int kc = 0; kc < 2; ++kc)
            xf[hh][kc] = *(const s16x8*)&xh[hh * 4608 + (16 * w + l16) * 72 + kc * 32 + quad * 8];

    f32x4 acc[3][2][4];
    #pragma unroll
    for (int p = 0; p < 3; ++p)
        #pragma unroll
        for (int hh = 0; hh < 2; ++hh)
            #pragma unroll
            for (int nt = 0; nt < 4; ++nt)
                acc[p][hh][nt] = (f32x4){0.f, 0.f, 0.f, 0.f};

    #pragma unroll
    for (int p = 0; p < 3; ++p)
        #pragma unroll
        for (int hh = 0; hh < 2; ++hh)
            #pragma unroll
            for (int nt = 0; nt < 4; ++nt)
                #pragma unroll
                for (int kc = 0; kc < 2; ++kc) {
                    const s16x8 wf = *(const s16x8*)&wt[
                        (size_t)((p * 16 + 2 * hp + hh) * 64 + nt * 16 + l16) * 64 + kc * 32 + quad * 8];
                    if (p < 2)  // Q,K: C[t][d] = X[t][i] * W[i][d]
                        acc[p][hh][nt] = mfma_bf16(xf[hh][kc], wf, acc[p][hh][nt]);
                    else        // V: C[d][t] = W^T[d][i] * X^T[i][t]
                        acc[p][hh][nt] = mfma_bf16(wf, xf[hh][kc], acc[p][hh][nt]);
                }

    // fused RoPE on Q,K: pairs (d, h0)<->(d, h0+1), j = d*8 + hp
    #pragma unroll
    for (int nt = 0; nt < 4; ++nt) {
        int d = nt * 16 + l16;
        float f = exp2f((float)(d * 8 + hp) * -0.02595256324130751f); // -log2(1e4)/512
        #pragma unroll
        for (int r = 0; r < 4; ++r) {
            float ang = (float)(t0 + 16 * w + quad * 4 + r) * f;
            float s, c;
            sincosf(ang, &s, &c);
            float a0 = acc[0][0][nt][r], a1 = acc[0][1][nt][r];
            acc[0][0][nt][r] = a0 * c - a1 * s;
            acc[0][1][nt][r] = a0 * s + a1 * c;
            float k0 = acc[1][0][nt][r], k1 = acc[1][1][nt][r];
            acc[1][0][nt][r] = k0 * c - k1 * s;
            acc[1][1][nt][r] = k0 * s + k1 * c;
        }
    }

    // store 6 tiles (Q,K as [t][d]; V as [d][t]) via LDS for coalescing
    #pragma unroll
    for (int p = 0; p < 3; ++p)
        #pragma unroll
        for (int hh = 0; hh < 2; ++hh) {
            __syncthreads();
            if (p < 2) {
                #pragma unroll
                for (int nt = 0; nt < 4; ++nt)
                    #pragma unroll
                    for (int r = 0; r < 4; ++r)
                        outl[(16 * w + quad * 4 + r) * 68 + nt * 16 + l16] = f2bf(acc[p][hh][nt][r]);
            } else {
                #pragma unroll
                for (int mt = 0; mt < 4; ++mt)
                    #pragma unroll
                    for (int r = 0; r < 4; ++r)
                        outl[(mt * 16 + quad * 4 + r) * 68 + 16 * w + l16] = f2bf(acc[p][hh][mt][r]);
            }
            __syncthreads();
            int h = 2 * hp + hh;
            if (p < 2) {
                unsigned short* g = (p == 0 ? Qt : Kt) + ((size_t)(b * 16 + h) * T_ + t0) * 64;
                for (int n = 2 * tid; n < 4096; n += 512) {
                    int t = n >> 6, dd = n & 63;
                    *(unsigned int*)(g + n) = *(const unsigned int*)&outl[t * 68 + dd];
                }
            } else {
                unsigned short* g = Vt + (size_t)(b * 16 + h) * 64 * T_;
                for (int n = 2 * tid; n < 4096; n += 512) {
                    int d = n >> 6, tt = n & 63;
                    *(unsigned int*)(g + d * T_ + t0 + tt) = *(const unsigned int*)&outl[d * 68 + tt];
                }
            }
        }
}

// ---------------- kernel 3: flash attention (software-pipelined) -----------
// block: 512 thr (8 waves), 32 q-rows. Wave w owns d-slice [128w,128w+128).
// launch_bounds (512,2): static register demand is ~215 VGPR/lane (Y=64,
// qf=32, vf=32, kn=32, S=16 + temps). The default budget (128) spilled all
// of it to scratch — the dominant cost of rounds 0/1. (512,2) gives a
// 256-reg budget: zero spill, 1 block/CU resident.
// Pipeline per k-tile:
//   phase A: issue V(kt) + K(kt+1) global loads, then softmax(kt)  (loads
//            drain under softmax at the A barrier)
//   phase B: PV(kt) MFMA with vf regs + S(kt+1) MFMA with kn regs
__global__ __launch_bounds__(512, 2) void k_attn(const unsigned short* __restrict__ Qt,
                                              const unsigned short* __restrict__ Kt,
                                              const unsigned short* __restrict__ Vt,
                                              float* __restrict__ out) {
    int bid = blockIdx.x;
    int j = bid >> 2, b = bid & 3;
    int qt = (bid < 256) ? (127 - j) : (j - 64);   // heavy blocks first (causal balance)
    int q0 = qt * 32;
    int tid = threadIdx.x, w = tid >> 6, lane = tid & 63;
    int quad = lane >> 4, l16 = lane & 15;

    __shared__ alignas(16) float S_red[8][32][36];          // partial S^T per wave, padded
    __shared__ alignas(16) unsigned short P_lds[32][40];    // P[q][kpos] bf16, padded
    __shared__ float m_st[32], l_st[32], alpha_s[32];

    if (tid < 32) { m_st[tid] = -INFINITY; l_st[tid] = 0.f; }

    // Q fragments (loop-invariant): B-operand, [q][d] d-contig
    s16x8 qf[2][4];
    #pragma unroll
    for (int qs = 0; qs < 2; ++qs)
        #pragma unroll
        for (int c = 0; c < 4; ++c) {
            int dg = w * 128 + c * 32 + quad * 8;
            int head = dg >> 6, d64 = dg & 63;
            qf[qs][c] = *(const s16x8*)&Qt[((size_t)(b * 16 + head) * T_ + q0 + qs * 16 + l16) * 64 + d64];
        }

    f32x4 Y[8][2];
    #pragma unroll
    for (int mt = 0; mt < 8; ++mt) { Y[mt][0] = (f32x4){0,0,0,0}; Y[mt][1] = (f32x4){0,0,0,0}; }

    const float gamma = 0.03125f;   // 1/sqrt(1024)
    int rq = tid >> 4;              // reduction-phase row 0..31 (16 lanes per row)
    int kk = (tid & 15) * 2;
    int nkt = qt + 1;

    // ---- prologue: S(0) into S_red ----
    {
        f32x4 S[2][2];
        S[0][0] = (f32x4){0,0,0,0}; S[0][1] = (f32x4){0,0,0,0};
        S[1][0] = (f32x4){0,0,0,0}; S[1][1] = (f32x4){0,0,0,0};
        #pragma unroll
        for (int kps = 0; kps < 2; ++kps)
            #pragma unroll
            for (int c = 0; c < 4; ++c) {
                int dg = w * 128 + c * 32 + quad * 8;
                int head = dg >> 6, d64 = dg & 63;
                s16x8 kf = *(const s16x8*)&Kt[((size_t)(b * 16 + head) * T_ + kps * 16 + l16) * 64 + d64];
                S[kps][0] = mfma_bf16(kf, qf[0][c], S[kps][0]);
                S[kps][1] = mfma_bf16(kf, qf[1][c], S[kps][1]);
            }
        #pragma unroll
        for (int kps = 0; kps < 2; ++kps)
            #pragma unroll
            for (int qs = 0; qs < 2; ++qs)
                *(f32x4*)&S_red[w][qs * 16 + l16][kps * 16 + quad * 4] = S[kps][qs];
    }
    __syncthreads();

    s16x8 vf[8];        // V(kt) fragments, loaded in phase A(kt)
    s16x8 kn[2][4];     // K(kt+1) fragments, loaded in phase A(kt)

    for (int kt = 0; kt < nkt; ++kt) {
        int kbase = kt * 32;
        bool more = (kt + 1 < nkt);

        // ---- phase A: prefetch V(kt) + K(kt+1), then softmax(kt) ----
        #pragma unroll
        for (int mt = 0; mt < 8; ++mt) {
            int dg = w * 128 + mt * 16 + l16;
            int head = dg >> 6, d64 = dg & 63;
            vf[mt] = *(const s16x8*)&Vt[((size_t)(b * 16 + head) * 64 + d64) * T_ + kbase + quad * 8];
        }
        if (more) {
            #pragma unroll
            for (int kps = 0; kps < 2; ++kps)
                #pragma unroll
                for (int c = 0; c < 4; ++c) {
                    int dg = w * 128 + c * 32 + quad * 8;
                    int head = dg >> 6, d64 = dg & 63;
                    kn[kps][c] = *(const s16x8*)&Kt[
                        ((size_t)(b * 16 + head) * T_ + kbase + 32 + kps * 16 + l16) * 64 + d64];
                }
        }

        float s0 = 0.f, s1 = 0.f;
        #pragma unroll
        for (int sl = 0; sl < 8; ++sl) {
            f32x2 v = *(const f32x2*)&S_red[sl][rq][kk];
            s0 += v.x; s1 += v.y;
        }
        s0 *= gamma; s1 *= gamma;
        int qg = q0 + rq;
        if (kbase + kk > qg)     s0 = -INFINITY;
        if (kbase + kk + 1 > qg) s1 = -INFINITY;
        float mx = fmaxf(s0, s1);
        mx = fmaxf(mx, __shfl_xor(mx, 1));
        mx = fmaxf(mx, __shfl_xor(mx, 2));
        mx = fmaxf(mx, __shfl_xor(mx, 4));
        mx = fmaxf(mx, __shfl_xor(mx, 8));
        float m_old = m_st[rq];
        float m_new = fmaxf(m_old, mx);
        float alpha = __expf(m_old - m_new);
        float p0 = __expf(s0 - m_new), p1 = __expf(s1 - m_new);
        float ps = p0 + p1;
        ps += __shfl_xor(ps, 1); ps += __shfl_xor(ps, 2);
        ps += __shfl_xor(ps, 4); ps += __shfl_xor(ps, 8);
        if ((tid & 15) == 0) {
            l_st[rq] = alpha * l_st[rq] + ps;
            m_st[rq] = m_new;
            alpha_s[rq] = alpha;
        }
        unsigned int pp = (unsigned int)f2bf(p0) | ((unsigned int)f2bf(p1) << 16);
        *(unsigned int*)&P_lds[rq][kk] = pp;
        __syncthreads();

        // ---- phase B: PV(kt) with vf regs + S(kt+1) with kn regs ----
        float a0 = alpha_s[l16], a1 = alpha_s[16 + l16];
        s16x8 pf0 = *(const s16x8*)&P_lds[l16][quad * 8];
        s16x8 pf1 = *(const s16x8*)&P_lds[16 + l16][quad * 8];
        // skip the Y-rescale (128 AGPR-touching VALU ops) when no row's max
        // grew this tile (alpha==1 exactly) — exact, wave-uniform branch.
        int scale = __any((a0 < 1.f) || (a1 < 1.f));
        __builtin_amdgcn_s_setprio(1);
        if (scale) {
            #pragma unroll
            for (int mt = 0; mt < 8; ++mt) {
                Y[mt][0] *= a0;
                Y[mt][1] *= a1;
                Y[mt][0] = mfma_bf16(vf[mt], pf0, Y[mt][0]);
                Y[mt][1] = mfma_bf16(vf[mt], pf1, Y[mt][1]);
            }
        } else {
            #pragma unroll
            for (int mt = 0; mt < 8; ++mt) {
                Y[mt][0] = mfma_bf16(vf[mt], pf0, Y[mt][0]);
                Y[mt][1] = mfma_bf16(vf[mt], pf1, Y[mt][1]);
            }
        }
        if (more) {
            f32x4 S[2][2];
            S[0][0] = (f32x4){0,0,0,0}; S[0][1] = (f32x4){0,0,0,0};
            S[1][0] = (f32x4){0,0,0,0}; S[1][1] = (f32x4){0,0,0,0};
            #pragma unroll
            for (int kps = 0; kps < 2; ++kps)
                #pragma unroll
                for (int c = 0; c < 4; ++c) {
                    S[kps][0] = mfma_bf16(kn[kps][c], qf[0][c], S[kps][0]);
                    S[kps][1] = mfma_bf16(kn[kps][c], qf[1][c], S[kps][1]);
                }
            #pragma unroll
            for (int kps = 0; kps < 2; ++kps)
                #pragma unroll
                for (int qs = 0; qs < 2; ++qs)
                    *(f32x4*)&S_red[w][qs * 16 + l16][kps * 16 + quad * 4] = S[kps][qs];
        }
        __builtin_amdgcn_s_setprio(0);
        __syncthreads();
    }

    // ---- epilogue: normalize, map d->(h,d64)->e, store fp32 ----
    float inv0 = 1.f / l_st[l16], inv1 = 1.f / l_st[16 + l16];
    #pragma unroll
    for (int mt = 0; mt < 8; ++mt)
        #pragma unroll
        for (int r = 0; r < 4; ++r) {
            int dg = w * 128 + mt * 16 + quad * 4 + r;
            int head = dg >> 6, d64 = dg & 63;
            int e = d64 * 16 + head;
            out[(size_t)(b * T_ + q0 + l16) * D_ + e]      = Y[mt][0][r] * inv0;
            out[(size_t)(b * T_ + q0 + 16 + l16) * D_ + e] = Y[mt][1][r] * inv1;
        }
}

extern "C" void kernel_launch(void* const* d_in, const int* in_sizes, int n_in,
                              void* d_out, int out_size, void* d_ws, size_t ws_size,
                              hipStream_t stream) {
    const float* x  = (const float*)d_in[0];
    const float* wq = (const float*)d_in[1];
    const float* wk = (const float*)d_in[2];
    const float* wv = (const float*)d_in[3];
    unsigned short* ws = (unsigned short*)d_ws;

    // workspace layout (bf16 elements)
    const size_t WT_ELEMS  = 3 * 16 * 64 * 64;          // 196608
    const size_t QKV_ELEMS = (size_t)B_ * 16 * T_ * 64; // 16777216 each
    const size_t NEED_BYTES = (WT_ELEMS + 3 * QKV_ELEMS) * sizeof(unsigned short);
    if (ws_size < NEED_BYTES) return;

    unsigned short* wt = ws;
    unsigned short* Qt = ws + WT_ELEMS;
    unsigned short* Kt = Qt + QKV_ELEMS;
    unsigned short* Vt = Kt + QKV_ELEMS;
    float* outp = (float*)d_out;

    k_wtrans<<<48, 256, 0, stream>>>(wq, wk, wv, wt);
    k_qkv<<<2048, 256, 0, stream>>>(x, wt, Qt, Kt, Vt);
    k_attn<<<512, 512, 0, stream>>>(Qt, Kt, Vt, outp);
}

// Round 3
// 882.594 us; speedup vs baseline: 1.2382x; 1.1395x over previous
//
#include <hip/hip_runtime.h>
#include <cmath>

#define B_ 4
#define T_ 4096
#define D_ 1024

typedef __attribute__((ext_vector_type(4))) float f32x4;
typedef __attribute__((ext_vector_type(2))) float f32x2;
typedef __attribute__((ext_vector_type(8))) short s16x8;

__device__ __forceinline__ f32x4 mfma_bf16(s16x8 a, s16x8 b, f32x4 c) {
    return __builtin_amdgcn_mfma_f32_16x16x32_bf16(a, b, c, 0, 0, 0);
}
__device__ __forceinline__ unsigned short f2bf(float f) {
    union { float f; unsigned int u; } v; v.f = f;
    unsigned int r = v.u + 0x7FFFu + ((v.u >> 16) & 1u);
    return (unsigned short)(r >> 16);
}

// ---------------- kernel 1: repack fp32 weights to bf16 w_t[p][h][d][i] ----
__global__ __launch_bounds__(256) void k_wtrans(const float* __restrict__ wq,
                                                const float* __restrict__ wk,
                                                const float* __restrict__ wv,
                                                unsigned short* __restrict__ wt) {
    int p = blockIdx.x >> 4;   // 0..2
    int h = blockIdx.x & 15;
    const float* src = (p == 0) ? wq : (p == 1) ? wk : wv;
    unsigned short* dst = wt + (size_t)((p * 16 + h) * 64) * 64;
    for (int idx = threadIdx.x; idx < 64 * 64; idx += 256) {
        int d = idx >> 6, i = idx & 63;
        dst[d * 64 + i] = f2bf(src[i * 1024 + d * 16 + h]);   // w[i][d][h]
    }
}

// ---------------- kernel 2: QKV projection + fused RoPE ---------------------
// block: 256 thr (4 waves), handles (b, head-pair hp, 64 tokens).
// Q_t,K_t: [b][h][t][d] (d-contig).
// V_t: tile-blocked [b][h][kt32][d64][t&31] so k_attn's V fragment loads are
//      fully contiguous (1KB per wave-instr) and line-exact.
// bid map: hp in HIGH bits so the 8 hp-blocks sharing an x-tile land on the
// SAME XCD -> x cachelines (which interleave all 16 heads) are L2-reused 8x.
__global__ __launch_bounds__(256, 3) void k_qkv(const float* __restrict__ x,
                                             const unsigned short* __restrict__ wt,
                                             unsigned short* __restrict__ Qt,
                                             unsigned short* __restrict__ Kt,
                                             unsigned short* __restrict__ Vt) {
    int bid = blockIdx.x;
    int hp  = bid >> 8;          // head pair 0..7
    int b   = (bid >> 6) & 3;
    int tc  = bid & 63;          // token chunk (64 tokens)
    int t0  = tc * 64;
    int tid = threadIdx.x, w = tid >> 6, lane = tid & 63;
    int quad = lane >> 4, l16 = lane & 15;

    __shared__ alignas(16) unsigned short xh[2 * 64 * 72];   // [hh][t][i], pad 72
    __shared__ alignas(16) unsigned short outl[64 * 68];     // staging tile, pad 68

    // the two hh values are adjacent in x (e = i*16 + 2hp + hh) -> f32x2 load
    for (int n = tid; n < 4096; n += 256) {
        int t = n >> 6, i = n & 63;
        f32x2 v = *(const f32x2*)&x[(size_t)(b * T_ + t0 + t) * D_ + i * 16 + 2 * hp];
        xh[t * 72 + i]        = f2bf(v.x);
        xh[4608 + t * 72 + i] = f2bf(v.y);
    }
    __syncthreads();

    s16x8 xf[2][2];
    #pragma unroll
    for (int hh = 0; hh < 2; ++hh)
        #pragma unroll
        for (int kc = 0; kc < 2; ++kc)
            xf[hh][kc] = *(const s16x8*)&xh[hh * 4608 + (16 * w + l16) * 72 + kc * 32 + quad * 8];

    f32x4 acc[3][2][4];
    #pragma unroll
    for (int p = 0; p < 3; ++p)
        #pragma unroll
        for (int hh = 0; hh < 2; ++hh)
            #pragma unroll
            for (int nt = 0; nt < 4; ++nt)
                acc[p][hh][nt] = (f32x4){0.f, 0.f, 0.f, 0.f};

    #pragma unroll
    for (int p = 0; p < 3; ++p)
        #pragma unroll
        for (int hh = 0; hh < 2; ++hh)
            #pragma unroll
            for (int nt = 0; nt < 4; ++nt)
                #pragma unroll
                for (int kc = 0; kc < 2; ++kc) {
                    const s16x8 wf = *(const s16x8*)&wt[
                        (size_t)((p * 16 + 2 * hp + hh) * 64 + nt * 16 + l16) * 64 + kc * 32 + quad * 8];
                    if (p < 2)  // Q,K: C[t][d] = X[t][i] * W[i][d]
                        acc[p][hh][nt] = mfma_bf16(xf[hh][kc], wf, acc[p][hh][nt]);
                    else        // V: C[d][t] = W^T[d][i] * X^T[i][t]
                        acc[p][hh][nt] = mfma_bf16(wf, xf[hh][kc], acc[p][hh][nt]);
                }

    // fused RoPE on Q,K: pairs (d, h0)<->(d, h0+1), j = d*8 + hp
    #pragma unroll
    for (int nt = 0; nt < 4; ++nt) {
        int d = nt * 16 + l16;
        float f = exp2f((float)(d * 8 + hp) * -0.02595256324130751f); // -log2(1e4)/512
        #pragma unroll
        for (int r = 0; r < 4; ++r) {
            float ang = (float)(t0 + 16 * w + quad * 4 + r) * f;
            float s, c;
            sincosf(ang, &s, &c);
            float a0 = acc[0][0][nt][r], a1 = acc[0][1][nt][r];
            acc[0][0][nt][r] = a0 * c - a1 * s;
            acc[0][1][nt][r] = a0 * s + a1 * c;
            float k0 = acc[1][0][nt][r], k1 = acc[1][1][nt][r];
            acc[1][0][nt][r] = k0 * c - k1 * s;
            acc[1][1][nt][r] = k0 * s + k1 * c;
        }
    }

    // store 6 tiles (Q,K as [t][d]; V tile-blocked) via LDS for coalescing
    #pragma unroll
    for (int p = 0; p < 3; ++p)
        #pragma unroll
        for (int hh = 0; hh < 2; ++hh) {
            __syncthreads();
            if (p < 2) {
                #pragma unroll
                for (int nt = 0; nt < 4; ++nt)
                    #pragma unroll
                    for (int r = 0; r < 4; ++r)
                        outl[(16 * w + quad * 4 + r) * 68 + nt * 16 + l16] = f2bf(acc[p][hh][nt][r]);
            } else {
                #pragma unroll
                for (int mt = 0; mt < 4; ++mt)
                    #pragma unroll
                    for (int r = 0; r < 4; ++r)
                        outl[(mt * 16 + quad * 4 + r) * 68 + 16 * w + l16] = f2bf(acc[p][hh][mt][r]);
            }
            __syncthreads();
            int h = 2 * hp + hh;
            if (p < 2) {
                unsigned short* g = (p == 0 ? Qt : Kt) + ((size_t)(b * 16 + h) * T_ + t0) * 64;
                for (int n = 2 * tid; n < 4096; n += 512) {
                    int t = n >> 6, dd = n & 63;
                    *(unsigned int*)(g + n) = *(const unsigned int*)&outl[t * 68 + dd];
                }
            } else {
                // tile-blocked V: [h][tile(128)][d64][t&31], tile = t>>5
                unsigned short* g = Vt + (size_t)(b * 16 + h) * 64 * T_;
                for (int n = 2 * tid; n < 4096; n += 512) {
                    int d = n >> 6, tt = n & 63;   // tt even; pair stays in one tile
                    int tile = 2 * tc + (tt >> 5);
                    *(unsigned int*)(g + (size_t)tile * 2048 + d * 32 + (tt & 31)) =
                        *(const unsigned int*)&outl[d * 68 + tt];
                }
            }
        }
}

// ---------------- kernel 3: flash attention (XCD-partitioned) --------------
// block: 512 thr (8 waves), 32 q-rows. Wave w owns d-slice [128w,128w+128).
// bid map (the round-3 lever): b = (bid>>1)&3 depends only on bid&7, so with
// round-robin dispatch XCD pair {2b,2b+1} runs ONLY batch b. All ~64 blocks
// on an XCD scan the same K/V(b) from kt=0 in near-lockstep -> each 128KB
// k-tile is fetched into the XCD's L2 once and reused ~64x (previously every
// XCD streamed all 4 batches from L3: zero reuse, fabric-BW bound at ~6.4TB/s
// with all util counters <10%).
// Pairing kept balanced: CU c gets bids {c, c+256} = qt (127-q) and (q):
// 129 iters total per CU.
__global__ __launch_bounds__(512, 2) void k_attn(const unsigned short* __restrict__ Qt,
                                              const unsigned short* __restrict__ Kt,
                                              const unsigned short* __restrict__ Vt,
                                              float* __restrict__ out) {
    int bid = blockIdx.x;
    int b = (bid >> 1) & 3;                      // batch <- XCD pair
    int q = ((bid >> 3) & 31) * 2 + (bid & 1);   // 0..63
    int qt = (bid < 256) ? (127 - q) : q;        // heavy blocks first
    int q0 = qt * 32;
    int tid = threadIdx.x, w = tid >> 6, lane = tid & 63;
    int quad = lane >> 4, l16 = lane & 15;

    __shared__ alignas(16) float S_red[8][32][36];          // partial S^T per wave, padded
    __shared__ alignas(16) unsigned short P_lds[32][40];    // P[q][kpos] bf16, padded
    __shared__ float m_st[32], l_st[32], alpha_s[32];

    if (tid < 32) { m_st[tid] = -INFINITY; l_st[tid] = 0.f; }

    // Q fragments (loop-invariant): B-operand, [q][d] d-contig
    s16x8 qf[2][4];
    #pragma unroll
    for (int qs = 0; qs < 2; ++qs)
        #pragma unroll
        for (int c = 0; c < 4; ++c) {
            int dg = w * 128 + c * 32 + quad * 8;
            int head = dg >> 6, d64 = dg & 63;
            qf[qs][c] = *(const s16x8*)&Qt[((size_t)(b * 16 + head) * T_ + q0 + qs * 16 + l16) * 64 + d64];
        }

    f32x4 Y[8][2];
    #pragma unroll
    for (int mt = 0; mt < 8; ++mt) { Y[mt][0] = (f32x4){0,0,0,0}; Y[mt][1] = (f32x4){0,0,0,0}; }

    const float gamma = 0.03125f;   // 1/sqrt(1024)
    int rq = tid >> 4;              // reduction-phase row 0..31 (16 lanes per row)
    int kk = (tid & 15) * 2;
    int nkt = qt + 1;

    // ---- prologue: S(0) into S_red ----
    {
        f32x4 S[2][2];
        S[0][0] = (f32x4){0,0,0,0}; S[0][1] = (f32x4){0,0,0,0};
        S[1][0] = (f32x4){0,0,0,0}; S[1][1] = (f32x4){0,0,0,0};
        #pragma unroll
        for (int kps = 0; kps < 2; ++kps)
            #pragma unroll
            for (int c = 0; c < 4; ++c) {
                int dg = w * 128 + c * 32 + quad * 8;
                int head = dg >> 6, d64 = dg & 63;
                s16x8 kf = *(const s16x8*)&Kt[((size_t)(b * 16 + head) * T_ + kps * 16 + l16) * 64 + d64];
                S[kps][0] = mfma_bf16(kf, qf[0][c], S[kps][0]);
                S[kps][1] = mfma_bf16(kf, qf[1][c], S[kps][1]);
            }
        #pragma unroll
        for (int kps = 0; kps < 2; ++kps)
            #pragma unroll
            for (int qs = 0; qs < 2; ++qs)
                *(f32x4*)&S_red[w][qs * 16 + l16][kps * 16 + quad * 4] = S[kps][qs];
    }
    __syncthreads();

    s16x8 vf[8];        // V(kt) fragments, loaded in phase A(kt)
    s16x8 kn[2][4];     // K(kt+1) fragments, loaded in phase A(kt)

    for (int kt = 0; kt < nkt; ++kt) {
        int kbase = kt * 32;
        bool more = (kt + 1 < nkt);

        // ---- phase A: prefetch V(kt) + K(kt+1), then softmax(kt) ----
        #pragma unroll
        for (int mt = 0; mt < 8; ++mt) {
            int dg = w * 128 + mt * 16 + l16;
            int head = dg >> 6, d64 = dg & 63;
            // tile-blocked V: contiguous 1KB per wave-instr
            vf[mt] = *(const s16x8*)&Vt[
                (((size_t)(b * 16 + head) * 128 + kt) * 64 + d64) * 32 + quad * 8];
        }
        if (more) {
            #pragma unroll
            for (int kps = 0; kps < 2; ++kps)
                #pragma unroll
                for (int c = 0; c < 4; ++c) {
                    int dg = w * 128 + c * 32 + quad * 8;
                    int head = dg >> 6, d64 = dg & 63;
                    kn[kps][c] = *(const s16x8*)&Kt[
                        ((size_t)(b * 16 + head) * T_ + kbase + 32 + kps * 16 + l16) * 64 + d64];
                }
        }

        float s0 = 0.f, s1 = 0.f;
        #pragma unroll
        for (int sl = 0; sl < 8; ++sl) {
            f32x2 v = *(const f32x2*)&S_red[sl][rq][kk];
            s0 += v.x; s1 += v.y;
        }
        s0 *= gamma; s1 *= gamma;
        int qg = q0 + rq;
        if (kbase + kk > qg)     s0 = -INFINITY;
        if (kbase + kk + 1 > qg) s1 = -INFINITY;
        float mx = fmaxf(s0, s1);
        mx = fmaxf(mx, __shfl_xor(mx, 1));
        mx = fmaxf(mx, __shfl_xor(mx, 2));
        mx = fmaxf(mx, __shfl_xor(mx, 4));
        mx = fmaxf(mx, __shfl_xor(mx, 8));
        float m_old = m_st[rq];
        float m_new = fmaxf(m_old, mx);
        float alpha = __expf(m_old - m_new);
        float p0 = __expf(s0 - m_new), p1 = __expf(s1 - m_new);
        float ps = p0 + p1;
        ps += __shfl_xor(ps, 1); ps += __shfl_xor(ps, 2);
        ps += __shfl_xor(ps, 4); ps += __shfl_xor(ps, 8);
        if ((tid & 15) == 0) {
            l_st[rq] = alpha * l_st[rq] + ps;
            m_st[rq] = m_new;
            alpha_s[rq] = alpha;
        }
        unsigned int pp = (unsigned int)f2bf(p0) | ((unsigned int)f2bf(p1) << 16);
        *(unsigned int*)&P_lds[rq][kk] = pp;
        __syncthreads();

        // ---- phase B: PV(kt) with vf regs + S(kt+1) with kn regs ----
        float a0 = alpha_s[l16], a1 = alpha_s[16 + l16];
        s16x8 pf0 = *(const s16x8*)&P_lds[l16][quad * 8];
        s16x8 pf1 = *(const s16x8*)&P_lds[16 + l16][quad * 8];
        // skip the Y-rescale when no row's max grew this tile (alpha==1
        // exactly) — exact, wave-uniform branch.
        int scale = __any((a0 < 1.f) || (a1 < 1.f));
        __builtin_amdgcn_s_setprio(1);
        if (scale) {
            #pragma unroll
            for (int mt = 0; mt < 8; ++mt) {
                Y[mt][0] *= a0;
                Y[mt][1] *= a1;
                Y[mt][0] = mfma_bf16(vf[mt], pf0, Y[mt][0]);
                Y[mt][1] = mfma_bf16(vf[mt], pf1, Y[mt][1]);
            }
        } else {
            #pragma unroll
            for (int mt = 0; mt < 8; ++mt) {
                Y[mt][0] = mfma_bf16(vf[mt], pf0, Y[mt][0]);
                Y[mt][1] = mfma_bf16(vf[mt], pf1, Y[mt][1]);
            }
        }
        if (more) {
            f32x4 S[2][2];
            S[0][0] = (f32x4){0,0,0,0}; S[0][1] = (f32x4){0,0,0,0};
            S[1][0] = (f32x4){0,0,0,0}; S[1][1] = (f32x4){0,0,0,0};
            #pragma unroll
            for (int kps = 0; kps < 2; ++kps)
                #pragma unroll
                for (int c = 0; c < 4; ++c) {
                    S[kps][0] = mfma_bf16(kn[kps][c], qf[0][c], S[kps][0]);
                    S[kps][1] = mfma_bf16(kn[kps][c], qf[1][c], S[kps][1]);
                }
            #pragma unroll
            for (int kps = 0; kps < 2; ++kps)
                #pragma unroll
                for (int qs = 0; qs < 2; ++qs)
                    *(f32x4*)&S_red[w][qs * 16 + l16][kps * 16 + quad * 4] = S[kps][qs];
        }
        __builtin_amdgcn_s_setprio(0);
        __syncthreads();
    }

    // ---- epilogue: normalize, map d->(h,d64)->e, store fp32 ----
    float inv0 = 1.f / l_st[l16], inv1 = 1.f / l_st[16 + l16];
    #pragma unroll
    for (int mt = 0; mt < 8; ++mt)
        #pragma unroll
        for (int r = 0; r < 4; ++r) {
            int dg = w * 128 + mt * 16 + quad * 4 + r;
            int head = dg >> 6, d64 = dg & 63;
            int e = d64 * 16 + head;
            out[(size_t)(b * T_ + q0 + l16) * D_ + e]      = Y[mt][0][r] * inv0;
            out[(size_t)(b * T_ + q0 + 16 + l16) * D_ + e] = Y[mt][1][r] * inv1;
        }
}

extern "C" void kernel_launch(void* const* d_in, const int* in_sizes, int n_in,
                              void* d_out, int out_size, void* d_ws, size_t ws_size,
                              hipStream_t stream) {
    const float* x  = (const float*)d_in[0];
    const float* wq = (const float*)d_in[1];
    const float* wk = (const float*)d_in[2];
    const float* wv = (const float*)d_in[3];
    unsigned short* ws = (unsigned short*)d_ws;

    // workspace layout (bf16 elements)
    const size_t WT_ELEMS  = 3 * 16 * 64 * 64;          // 196608
    const size_t QKV_ELEMS = (size_t)B_ * 16 * T_ * 64; // 16777216 each
    const size_t NEED_BYTES = (WT_ELEMS + 3 * QKV_ELEMS) * sizeof(unsigned short);
    if (ws_size < NEED_BYTES) return;

    unsigned short* wt = ws;
    unsigned short* Qt = ws + WT_ELEMS;
    unsigned short* Kt = Qt + QKV_ELEMS;
    unsigned short* Vt = Kt + QKV_ELEMS;
    float* outp = (float*)d_out;

    k_wtrans<<<48, 256, 0, stream>>>(wq, wk, wv, wt);
    k_qkv<<<2048, 256, 0, stream>>>(x, wt, Qt, Kt, Vt);
    k_attn<<<512, 512, 0, stream>>>(Qt, Kt, Vt, outp);
}

// Round 4
// 709.594 us; speedup vs baseline: 1.5401x; 1.2438x over previous
//
#include <hip/hip_runtime.h>
#include <cmath>

#define B_ 4
#define T_ 4096
#define D_ 1024

typedef __attribute__((ext_vector_type(4))) float f32x4;
typedef __attribute__((ext_vector_type(2))) float f32x2;
typedef __attribute__((ext_vector_type(8))) short s16x8;

__device__ __forceinline__ f32x4 mfma_bf16(s16x8 a, s16x8 b, f32x4 c) {
    return __builtin_amdgcn_mfma_f32_16x16x32_bf16(a, b, c, 0, 0, 0);
}
__device__ __forceinline__ unsigned short f2bf(float f) {
    union { float f; unsigned int u; } v; v.f = f;
    unsigned int r = v.u + 0x7FFFu + ((v.u >> 16) & 1u);
    return (unsigned short)(r >> 16);
}
// DPP lane permute within 16-lane rows (VALU-speed, replaces ds_bpermute shfl)
template <int CTRL>
__device__ __forceinline__ float dppf(float x) {
    return __int_as_float(
        __builtin_amdgcn_mov_dpp(__float_as_int(x), CTRL, 0xF, 0xF, true));
}
// 16-lane reduction: quad_perm[1,0,3,2]=0xB1 (xor1), [2,3,0,1]=0x4E (xor2),
// row_half_mirror=0x141 (combines quad pairs), row_mirror=0x140 (halves)
__device__ __forceinline__ float rowmax16(float v) {
    v = fmaxf(v, dppf<0xB1>(v));
    v = fmaxf(v, dppf<0x4E>(v));
    v = fmaxf(v, dppf<0x141>(v));
    v = fmaxf(v, dppf<0x140>(v));
    return v;
}
__device__ __forceinline__ float rowsum16(float v) {
    v += dppf<0xB1>(v);
    v += dppf<0x4E>(v);
    v += dppf<0x141>(v);
    v += dppf<0x140>(v);
    return v;
}

// ---------------- kernel 1: repack fp32 weights to bf16 w_t[p][h][d][i] ----
__global__ __launch_bounds__(256) void k_wtrans(const float* __restrict__ wq,
                                                const float* __restrict__ wk,
                                                const float* __restrict__ wv,
                                                unsigned short* __restrict__ wt) {
    int p = blockIdx.x >> 4;   // 0..2
    int h = blockIdx.x & 15;
    const float* src = (p == 0) ? wq : (p == 1) ? wk : wv;
    unsigned short* dst = wt + (size_t)((p * 16 + h) * 64) * 64;
    for (int idx = threadIdx.x; idx < 64 * 64; idx += 256) {
        int d = idx >> 6, i = idx & 63;
        dst[d * 64 + i] = f2bf(src[i * 1024 + d * 16 + h]);   // w[i][d][h]
    }
}

// ---------------- kernel 2: QKV projection + fused RoPE ---------------------
// (unchanged from round 3)
__global__ __launch_bounds__(256, 3) void k_qkv(const float* __restrict__ x,
                                             const unsigned short* __restrict__ wt,
                                             unsigned short* __restrict__ Qt,
                                             unsigned short* __restrict__ Kt,
                                             unsigned short* __restrict__ Vt) {
    int bid = blockIdx.x;
    int hp  = bid >> 8;          // head pair 0..7
    int b   = (bid >> 6) & 3;
    int tc  = bid & 63;          // token chunk (64 tokens)
    int t0  = tc * 64;
    int tid = threadIdx.x, w = tid >> 6, lane = tid & 63;
    int quad = lane >> 4, l16 = lane & 15;

    __shared__ alignas(16) unsigned short xh[2 * 64 * 72];   // [hh][t][i], pad 72
    __shared__ alignas(16) unsigned short outl[64 * 68];     // staging tile, pad 68

    for (int n = tid; n < 4096; n += 256) {
        int t = n >> 6, i = n & 63;
        f32x2 v = *(const f32x2*)&x[(size_t)(b * T_ + t0 + t) * D_ + i * 16 + 2 * hp];
        xh[t * 72 + i]        = f2bf(v.x);
        xh[4608 + t * 72 + i] = f2bf(v.y);
    }
    __syncthreads();

    s16x8 xf[2][2];
    #pragma unroll
    for (int hh = 0; hh < 2; ++hh)
        #pragma unroll
        for (int kc = 0; kc < 2; ++kc)
            xf[hh][kc] = *(const s16x8*)&xh[hh * 4608 + (16 * w + l16) * 72 + kc * 32 + quad * 8];

    f32x4 acc[3][2][4];
    #pragma unroll
    for (int p = 0; p < 3; ++p)
        #pragma unroll
        for (int hh = 0; hh < 2; ++hh)
            #pragma unroll
            for (int nt = 0; nt < 4; ++nt)
                acc[p][hh][nt] = (f32x4){0.f, 0.f, 0.f, 0.f};

    #pragma unroll
    for (int p = 0; p < 3; ++p)
        #pragma unroll
        for (int hh = 0; hh < 2; ++hh)
            #pragma unroll
            for (int nt = 0; nt < 4; ++nt)
                #pragma unroll
                for (int kc = 0; kc < 2; ++kc) {
                    const s16x8 wf = *(const s16x8*)&wt[
                        (size_t)((p * 16 + 2 * hp + hh) * 64 + nt * 16 + l16) * 64 + kc * 32 + quad * 8];
                    if (p < 2)
                        acc[p][hh][nt] = mfma_bf16(xf[hh][kc], wf, acc[p][hh][nt]);
                    else
                        acc[p][hh][nt] = mfma_bf16(wf, xf[hh][kc], acc[p][hh][nt]);
                }

    #pragma unroll
    for (int nt = 0; nt < 4; ++nt) {
        int d = nt * 16 + l16;
        float f = exp2f((float)(d * 8 + hp) * -0.02595256324130751f); // -log2(1e4)/512
        #pragma unroll
        for (int r = 0; r < 4; ++r) {
            float ang = (float)(t0 + 16 * w + quad * 4 + r) * f;
            float s, c;
            sincosf(ang, &s, &c);
            float a0 = acc[0][0][nt][r], a1 = acc[0][1][nt][r];
            acc[0][0][nt][r] = a0 * c - a1 * s;
            acc[0][1][nt][r] = a0 * s + a1 * c;
            float k0 = acc[1][0][nt][r], k1 = acc[1][1][nt][r];
            acc[1][0][nt][r] = k0 * c - k1 * s;
            acc[1][1][nt][r] = k0 * s + k1 * c;
        }
    }

    #pragma unroll
    for (int p = 0; p < 3; ++p)
        #pragma unroll
        for (int hh = 0; hh < 2; ++hh) {
            __syncthreads();
            if (p < 2) {
                #pragma unroll
                for (int nt = 0; nt < 4; ++nt)
                    #pragma unroll
                    for (int r = 0; r < 4; ++r)
                        outl[(16 * w + quad * 4 + r) * 68 + nt * 16 + l16] = f2bf(acc[p][hh][nt][r]);
            } else {
                #pragma unroll
                for (int mt = 0; mt < 4; ++mt)
                    #pragma unroll
                    for (int r = 0; r < 4; ++r)
                        outl[(mt * 16 + quad * 4 + r) * 68 + 16 * w + l16] = f2bf(acc[p][hh][mt][r]);
            }
            __syncthreads();
            int h = 2 * hp + hh;
            if (p < 2) {
                unsigned short* g = (p == 0 ? Qt : Kt) + ((size_t)(b * 16 + h) * T_ + t0) * 64;
                for (int n = 2 * tid; n < 4096; n += 512) {
                    int t = n >> 6, dd = n & 63;
                    *(unsigned int*)(g + n) = *(const unsigned int*)&outl[t * 68 + dd];
                }
            } else {
                // tile-blocked V: [h][tile(128)][d64][t&31], tile = t>>5
                unsigned short* g = Vt + (size_t)(b * 16 + h) * 64 * T_;
                for (int n = 2 * tid; n < 4096; n += 512) {
                    int d = n >> 6, tt = n & 63;
                    int tile = 2 * tc + (tt >> 5);
                    *(unsigned int*)(g + (size_t)tile * 2048 + d * 32 + (tt & 31)) =
                        *(const unsigned int*)&outl[d * 68 + tt];
                }
            }
        }
}

// ---------------- kernel 3: flash attention, KVBLK=64 ----------------------
// block: 512 thr (8 waves), 32 q-rows, 64-key tiles. Wave w owns d-slice
// [128w,128w+128). Per iter: phase A = softmax(64 keys) with DPP row-reduce
// (no ds_bpermute chains) + register m/l; phase B = PV (2 k-halves) + S-next.
// Fixed per-iter costs (2 barriers, reduce round trip, issue) amortize over
// 2x keys vs rounds 0-3.
__global__ __launch_bounds__(512, 2) void k_attn(const unsigned short* __restrict__ Qt,
                                              const unsigned short* __restrict__ Kt,
                                              const unsigned short* __restrict__ Vt,
                                              float* __restrict__ out) {
    int bid = blockIdx.x;
    int b = (bid >> 1) & 3;                      // batch <- XCD pair (round-3 win)
    int q = ((bid >> 3) & 31) * 2 + (bid & 1);   // 0..63
    int qt = (bid < 256) ? (127 - q) : q;        // heavy blocks first
    int q0 = qt * 32;
    int tid = threadIdx.x, w = tid >> 6, lane = tid & 63;
    int quad = lane >> 4, l16 = lane & 15;

    __shared__ alignas(16) float S_red[8][32][68];          // partial S^T, 64 keys, pad 68
    __shared__ alignas(16) unsigned short P_lds[32][72];    // P[q][kpos] bf16, pad 72
    __shared__ float alpha_s[32], l_st[32];

    // Q fragments (loop-invariant): B-operand, [q][d] d-contig
    s16x8 qf[2][4];
    #pragma unroll
    for (int qs = 0; qs < 2; ++qs)
        #pragma unroll
        for (int c = 0; c < 4; ++c) {
            int dg = w * 128 + c * 32 + quad * 8;
            int head = dg >> 6, d64 = dg & 63;
            qf[qs][c] = *(const s16x8*)&Qt[((size_t)(b * 16 + head) * T_ + q0 + qs * 16 + l16) * 64 + d64];
        }

    f32x4 Y[8][2];
    #pragma unroll
    for (int mt = 0; mt < 8; ++mt) { Y[mt][0] = (f32x4){0,0,0,0}; Y[mt][1] = (f32x4){0,0,0,0}; }

    const float gamma = 0.03125f;   // 1/sqrt(1024)
    int rq = tid >> 4;              // softmax row 0..31 (16 lanes per row)
    int kk4 = (tid & 15) * 4;       // 4 keys per thread
    int nkt = (qt >> 1) + 1;        // 64-key tiles
    float m_reg = -INFINITY, l_reg = 0.f;   // row-replicated (DPP keeps uniform)

    // ---- prologue: S(tile 0) = keys 0..63 into S_red ----
    {
        f32x4 S[4][2];
        #pragma unroll
        for (int kps = 0; kps < 4; ++kps) { S[kps][0] = (f32x4){0,0,0,0}; S[kps][1] = (f32x4){0,0,0,0}; }
        #pragma unroll
        for (int kps = 0; kps < 4; ++kps)
            #pragma unroll
            for (int c = 0; c < 4; ++c) {
                int dg = w * 128 + c * 32 + quad * 8;
                int head = dg >> 6, d64 = dg & 63;
                s16x8 kf = *(const s16x8*)&Kt[((size_t)(b * 16 + head) * T_ + kps * 16 + l16) * 64 + d64];
                S[kps][0] = mfma_bf16(kf, qf[0][c], S[kps][0]);
                S[kps][1] = mfma_bf16(kf, qf[1][c], S[kps][1]);
            }
        #pragma unroll
        for (int kps = 0; kps < 4; ++kps)
            #pragma unroll
            for (int qs = 0; qs < 2; ++qs)
                *(f32x4*)&S_red[w][qs * 16 + l16][kps * 16 + quad * 4] = S[kps][qs];
    }
    __syncthreads();

    s16x8 vfA[8];   // V keys [kbase, kbase+32), prefetched in phase A
    s16x8 vfB[8];   // V keys [kbase+32, kbase+64), loaded at phase-B start

    for (int kt = 0; kt < nkt; ++kt) {
        int kbase = kt * 64;
        bool more = (kt + 1 < nkt);

        // ---- phase A: prefetch V half-A, then softmax(64 keys) ----
        #pragma unroll
        for (int mt = 0; mt < 8; ++mt) {
            int dg = w * 128 + mt * 16 + l16;
            int head = dg >> 6, d64 = dg & 63;
            vfA[mt] = *(const s16x8*)&Vt[
                (((size_t)(b * 16 + head) * 128 + 2 * kt) * 64 + d64) * 32 + quad * 8];
        }

        f32x4 s = {0.f, 0.f, 0.f, 0.f};
        #pragma unroll
        for (int sl = 0; sl < 8; ++sl) {
            f32x4 v = *(const f32x4*)&S_red[sl][rq][kk4];
            s.x += v.x; s.y += v.y; s.z += v.z; s.w += v.w;
        }
        int qg = q0 + rq;
        int kb = kbase + kk4;
        s.x = (kb     > qg) ? -INFINITY : s.x * gamma;
        s.y = (kb + 1 > qg) ? -INFINITY : s.y * gamma;
        s.z = (kb + 2 > qg) ? -INFINITY : s.z * gamma;
        s.w = (kb + 3 > qg) ? -INFINITY : s.w * gamma;
        float mx = rowmax16(fmaxf(fmaxf(s.x, s.y), fmaxf(s.z, s.w)));
        float m_new = fmaxf(m_reg, mx);
        float alpha = __expf(m_reg - m_new);
        float p0 = __expf(s.x - m_new), p1 = __expf(s.y - m_new);
        float p2 = __expf(s.z - m_new), p3 = __expf(s.w - m_new);
        float ps = rowsum16((p0 + p1) + (p2 + p3));
        l_reg = alpha * l_reg + ps;
        m_reg = m_new;
        if ((tid & 15) == 0) alpha_s[rq] = alpha;
        unsigned int plo = (unsigned int)f2bf(p0) | ((unsigned int)f2bf(p1) << 16);
        unsigned int phi = (unsigned int)f2bf(p2) | ((unsigned int)f2bf(p3) << 16);
        *(unsigned long long*)&P_lds[rq][kk4] =
            (unsigned long long)plo | ((unsigned long long)phi << 32);
        __syncthreads();

        // ---- phase B: PV (2 halves) + S(next tile) ----
        // issue V half-B loads first; PV half-A MFMAs cover their latency
        #pragma unroll
        for (int mt = 0; mt < 8; ++mt) {
            int dg = w * 128 + mt * 16 + l16;
            int head = dg >> 6, d64 = dg & 63;
            vfB[mt] = *(const s16x8*)&Vt[
                (((size_t)(b * 16 + head) * 128 + 2 * kt + 1) * 64 + d64) * 32 + quad * 8];
        }
        float a0 = alpha_s[l16], a1 = alpha_s[16 + l16];
        s16x8 pf0a = *(const s16x8*)&P_lds[l16][quad * 8];
        s16x8 pf0b = *(const s16x8*)&P_lds[l16][32 + quad * 8];
        s16x8 pf1a = *(const s16x8*)&P_lds[16 + l16][quad * 8];
        s16x8 pf1b = *(const s16x8*)&P_lds[16 + l16][32 + quad * 8];
        int scale = __any((a0 < 1.f) || (a1 < 1.f));
        __builtin_amdgcn_s_setprio(1);
        if (scale) {
            #pragma unroll
            for (int mt = 0; mt < 8; ++mt) { Y[mt][0] *= a0; Y[mt][1] *= a1; }
        }
        #pragma unroll
        for (int mt = 0; mt < 8; ++mt) {
            Y[mt][0] = mfma_bf16(vfA[mt], pf0a, Y[mt][0]);
            Y[mt][1] = mfma_bf16(vfA[mt], pf1a, Y[mt][1]);
        }
        #pragma unroll
        for (int mt = 0; mt < 8; ++mt) {
            Y[mt][0] = mfma_bf16(vfB[mt], pf0b, Y[mt][0]);
            Y[mt][1] = mfma_bf16(vfB[mt], pf1b, Y[mt][1]);
        }
        if (more) {
            f32x4 S[4][2];
            #pragma unroll
            for (int kps = 0; kps < 4; ++kps) { S[kps][0] = (f32x4){0,0,0,0}; S[kps][1] = (f32x4){0,0,0,0}; }
            #pragma unroll
            for (int kps = 0; kps < 4; ++kps)
                #pragma unroll
                for (int c = 0; c < 4; ++c) {
                    int dg = w * 128 + c * 32 + quad * 8;
                    int head = dg >> 6, d64 = dg & 63;
                    s16x8 kf = *(const s16x8*)&Kt[
                        ((size_t)(b * 16 + head) * T_ + kbase + 64 + kps * 16 + l16) * 64 + d64];
                    S[kps][0] = mfma_bf16(kf, qf[0][c], S[kps][0]);
                    S[kps][1] = mfma_bf16(kf, qf[1][c], S[kps][1]);
                }
            #pragma unroll
            for (int kps = 0; kps < 4; ++kps)
                #pragma unroll
                for (int qs = 0; qs < 2; ++qs)
                    *(f32x4*)&S_red[w][qs * 16 + l16][kps * 16 + quad * 4] = S[kps][qs];
        }
        __builtin_amdgcn_s_setprio(0);
        __syncthreads();
    }

    // ---- epilogue: publish l, normalize, map d->(h,d64)->e, store fp32 ----
    if ((tid & 15) == 0) l_st[rq] = l_reg;
    __syncthreads();
    float inv0 = 1.f / l_st[l16], inv1 = 1.f / l_st[16 + l16];
    #pragma unroll
    for (int mt = 0; mt < 8; ++mt)
        #pragma unroll
        for (int r = 0; r < 4; ++r) {
            int dg = w * 128 + mt * 16 + quad * 4 + r;
            int head = dg >> 6, d64 = dg & 63;
            int e = d64 * 16 + head;
            out[(size_t)(b * T_ + q0 + l16) * D_ + e]      = Y[mt][0][r] * inv0;
            out[(size_t)(b * T_ + q0 + 16 + l16) * D_ + e] = Y[mt][1][r] * inv1;
        }
}

extern "C" void kernel_launch(void* const* d_in, const int* in_sizes, int n_in,
                              void* d_out, int out_size, void* d_ws, size_t ws_size,
                              hipStream_t stream) {
    const float* x  = (const float*)d_in[0];
    const float* wq = (const float*)d_in[1];
    const float* wk = (const float*)d_in[2];
    const float* wv = (const float*)d_in[3];
    unsigned short* ws = (unsigned short*)d_ws;

    const size_t WT_ELEMS  = 3 * 16 * 64 * 64;          // 196608
    const size_t QKV_ELEMS = (size_t)B_ * 16 * T_ * 64; // 16777216 each
    const size_t NEED_BYTES = (WT_ELEMS + 3 * QKV_ELEMS) * sizeof(unsigned short);
    if (ws_size < NEED_BYTES) return;

    unsigned short* wt = ws;
    unsigned short* Qt = ws + WT_ELEMS;
    unsigned short* Kt = Qt + QKV_ELEMS;
    unsigned short* Vt = Kt + QKV_ELEMS;
    float* outp = (float*)d_out;

    k_wtrans<<<48, 256, 0, stream>>>(wq, wk, wv, wt);
    k_qkv<<<2048, 256, 0, stream>>>(x, wt, Qt, Kt, Vt);
    k_attn<<<512, 512, 0, stream>>>(Qt, Kt, Vt, outp);
}